// Round 9
// baseline (905.548 us; speedup 1.0000x reference)
//
#include <hip/hip_runtime.h>
#include <hip/hip_bf16.h>
#include <math.h>

typedef __bf16 bf16x8 __attribute__((ext_vector_type(8)));
typedef float floatx4 __attribute__((ext_vector_type(4)));

__device__ __forceinline__ short f2b(float f) {
  __hip_bfloat16 h = __float2bfloat16(f);
  return *reinterpret_cast<short*>(&h);
}
__device__ __forceinline__ float b2f(short s) {
  unsigned u = ((unsigned)(unsigned short)s) << 16;
  float f;
  __builtin_memcpy(&f, &u, 4);
  return f;
}

// async global->LDS, 16B per lane; lds base must be wave-uniform
__device__ __forceinline__ void gl2lds16(const void* g, void* l) {
  __builtin_amdgcn_global_load_lds((__attribute__((address_space(1))) const void*)g,
                                   (__attribute__((address_space(3))) void*)l, 16, 0, 0);
}

// ---------------- block reduction helpers ----------------
__device__ __forceinline__ float block_sum(float v, float* sdata) {
#pragma unroll
  for (int o = 32; o > 0; o >>= 1) v += __shfl_down(v, o, 64);
  __syncthreads();
  int lane = threadIdx.x & 63, wid = threadIdx.x >> 6;
  if (lane == 0) sdata[wid] = v;
  __syncthreads();
  float s = 0.f;
  int nw = blockDim.x >> 6;
  for (int i = 0; i < nw; i++) s += sdata[i];
  return s;
}

// fused two-value block sum (one barrier pair for both)
__device__ __forceinline__ float2 block_sum2(float a, float b, float* sdata) {
#pragma unroll
  for (int o = 32; o > 0; o >>= 1) {
    a += __shfl_down(a, o, 64);
    b += __shfl_down(b, o, 64);
  }
  __syncthreads();
  int lane = threadIdx.x & 63, wid = threadIdx.x >> 6;
  if (lane == 0) { sdata[wid] = a; sdata[8 + wid] = b; }
  __syncthreads();
  float sa = 0.f, sb = 0.f;
  int nw = blockDim.x >> 6;
  for (int i = 0; i < nw; i++) { sa += sdata[i]; sb += sdata[8 + i]; }
  return make_float2(sa, sb);
}

// ---------------- conversion kernels ----------------
__global__ void cvt_kernel(const float* __restrict__ src, short* __restrict__ dst, long n4) {
  long i = (long)blockIdx.x * blockDim.x + threadIdx.x;
  if (i < n4) {
    float4 v = ((const float4*)src)[i];
    short4 o;
    o.x = f2b(v.x); o.y = f2b(v.y); o.z = f2b(v.z); o.w = f2b(v.w);
    ((short4*)dst)[i] = o;
  }
}

// dst[r*ldD + c] = bf16(src[r*ldS + c]); grid (C/32, R/32, nb), block (32,8)
__global__ void cvt2_kernel(const float* __restrict__ src, short* __restrict__ dst,
                            int ldS, int ldD, long sS, long sD) {
  src += (size_t)blockIdx.z * sS;
  dst += (size_t)blockIdx.z * sD;
  int c = blockIdx.x * 32 + threadIdx.x;
  int r0 = blockIdx.y * 32 + threadIdx.y;
#pragma unroll
  for (int i = 0; i < 32; i += 8)
    dst[(size_t)(r0 + i) * ldD + c] = f2b(src[(size_t)(r0 + i) * ldS + c]);
}

// dst[c*ldD + r] = bf16(src[r*ldS + c]); grid (C/32, R/32, nb), block (32,8)
__global__ void cvtT2_kernel(const float* __restrict__ src, short* __restrict__ dst,
                             int ldS, int ldD, long sS, long sD) {
  src += (size_t)blockIdx.z * sS;
  dst += (size_t)blockIdx.z * sD;
  __shared__ float tile[32][33];
  int r0 = blockIdx.y * 32, c0 = blockIdx.x * 32;
  int tx = threadIdx.x, ty = threadIdx.y;
#pragma unroll
  for (int i = 0; i < 32; i += 8)
    tile[ty + i][tx] = src[(size_t)(r0 + ty + i) * ldS + c0 + tx];
  __syncthreads();
#pragma unroll
  for (int i = 0; i < 32; i += 8)
    dst[(size_t)(c0 + ty + i) * ldD + r0 + tx] = f2b(tile[tx][ty + i]);
}

// ---------------- embed gather + norm; fills xsa, xsa_bf, xsaT_bf, z-slot of catA -----
__global__ void embed_norm_kernel(const int* __restrict__ masked,
                                  const float* __restrict__ embed,
                                  float* __restrict__ xsa, short* __restrict__ xsa_bf,
                                  short* __restrict__ xsaT_bf, short* __restrict__ catA,
                                  int E, int L, int ldA, int zoff) {
  int row = blockIdx.x;
  int g = masked[row];
  __shared__ float sdata[16];
  float x = embed[(size_t)g * E + threadIdx.x];
  float2 ss = block_sum2(x, x * x, sdata);
  float mean = ss.x / E;
  float var = fmaxf((ss.y - E * mean * mean) / (E - 1), 0.f);
  float val = x / (1.0f + sqrtf(var));
  size_t off = (size_t)row * E + threadIdx.x;
  xsa[off] = val;
  short b = f2b(val);
  xsa_bf[off] = b;
  catA[(size_t)row * ldA + zoff + threadIdx.x] = b;
  int bb = row / L, l = row - bb * L;
  xsaT_bf[((size_t)bb * E + threadIdx.x) * L + l] = b;
}

// ---------------- bf16 MFMA GEMM (NT), async dbuf, XOR swizzle, tiled ----------------
// C[m,n] = alpha*sum_k A[m,k]*B[n,k] [*1/rowsum] [+bias[n]] [relu] [exp2];
// BMxBN tile, BK=64, 4 waves 2x2.
// A-row roll (3 zones): shift = n0<ns1 ? shiftA : (n0<ns2 ? shiftB : 0), per Lroll rows.
// Dual output: if C2b && n0>=ncut, write bf16 to C2b at col gcol-ncut (no relu).
// ASUM: accumulate per-A-row sums via MFMA with ones-B; epilogue multiplies by 1/sum.
// ksplit: grid.z = nb*ksplit; K-slice kz handles K-range [kz*K/ksplit, ...); fp32 C
//         written to Cf + kz*ksC (caller sums the slices); bias applied only by kz==0.
template <int BM, int BN, int OUT_BF16, int ASUM>
__global__ __launch_bounds__(256) void bgemm_kernel(
    const short* __restrict__ A, int lda, long sA,
    const short* __restrict__ B, int ldb, long sB,
    void* __restrict__ Cv, int ldc, long sC,
    short* __restrict__ C2b, int ldc2, int ncut,
    int Ksz, float alpha, const float* __restrict__ bias,
    int relu, int expo, int shiftA, int shiftB, int ns1, int ns2, int Lroll,
    int ksplit, long ksC) {
  constexpr int WM = BM / 2, WN = BN / 2;
  constexpr int MT = WM / 16, NT = WN / 16;
  constexpr int NCH = (BM + BN) * 8;  // 16B chunks per K-tile
  constexpr int LPT = NCH / 256;      // chunk-groups per thread
  int bz = blockIdx.z, kz = 0;
  if (ksplit > 1) {
    bz = blockIdx.z / ksplit;
    kz = blockIdx.z - bz * ksplit;
  }
  int Kper = Ksz / ksplit;
  int koff = kz * Kper;
  A += (size_t)bz * sA + koff;
  B += (size_t)bz * sB + koff;
  float* Cf = (float*)Cv + (size_t)bz * sC + (size_t)kz * ksC;
  short* Cb = (short*)Cv + (size_t)bz * sC;
  int m0 = blockIdx.y * BM, n0 = blockIdx.x * BN;
  int shift = (n0 < ns1) ? shiftA : ((n0 < ns2) ? shiftB : 0);
  int zone2 = (C2b != nullptr) && (n0 >= ncut);
  __shared__ short S[2][(BM + BN) * 64];
  int tid = threadIdx.x, lane = tid & 63, w = tid >> 6;
  int wm = (w & 1) * WM, wn = (w >> 1) * WN;
  int ml = lane & 15, q4 = lane >> 4, sw = ml & 7;

  const short* src[LPT];
#pragma unroll
  for (int i = 0; i < LPT; i++) {
    int q = i * 256 + w * 64 + lane;
    if (q < BM * 8) {
      int m = q >> 3, cl = q & 7, cs = cl ^ (m & 7);
      int mg = m0 + m;
      if (shift != 0) {
        int bb = mg / Lroll, l = mg - bb * Lroll;
        l = (l + shift + Lroll) % Lroll;
        mg = bb * Lroll + l;
      }
      src[i] = A + (size_t)mg * lda + cs * 8;
    } else {
      int qb = q - BM * 8;
      int n = qb >> 3, cl = qb & 7, cs = cl ^ (n & 7);
      src[i] = B + (size_t)(n0 + n) * ldb + cs * 8;
    }
  }
  // prologue: stage tile 0
#pragma unroll
  for (int i = 0; i < LPT; i++)
    gl2lds16(src[i], &S[0][(i * 256 + w * 64) * 8]);
  floatx4 acc[MT][NT] = {};
  floatx4 sumacc[ASUM ? MT : 1] = {};
  bf16x8 ones;
#pragma unroll
  for (int i = 0; i < 8; i++) ones[i] = (__bf16)1.0f;
  int nT = Kper >> 6;
  for (int t = 0; t < nT; t++) {
    __syncthreads();  // drains vmcnt: tile t resident; all waves done with t-1
    int cur = t & 1;
    if (t + 1 < nT) {
      int nxt = cur ^ 1, ko = (t + 1) * 64;
#pragma unroll
      for (int i = 0; i < LPT; i++)
        gl2lds16(src[i] + ko, &S[nxt][(i * 256 + w * 64) * 8]);
    }
#pragma unroll
    for (int kk = 0; kk < 2; kk++) {
      int j = kk * 4 + q4;
      bf16x8 af[MT], bg[NT];
#pragma unroll
      for (int mt = 0; mt < MT; mt++) {
        int r = wm + mt * 16 + ml;
        af[mt] = *reinterpret_cast<const bf16x8*>(&S[cur][r * 64 + (j ^ sw) * 8]);
      }
#pragma unroll
      for (int nt = 0; nt < NT; nt++) {
        int r = wn + nt * 16 + ml;
        bg[nt] = *reinterpret_cast<const bf16x8*>(&S[cur][BM * 64 + r * 64 + (j ^ sw) * 8]);
      }
#pragma unroll
      for (int mt = 0; mt < MT; mt++)
#pragma unroll
        for (int nt = 0; nt < NT; nt++)
          acc[mt][nt] = __builtin_amdgcn_mfma_f32_16x16x32_bf16(af[mt], bg[nt], acc[mt][nt], 0, 0, 0);
      if (ASUM)
#pragma unroll
        for (int mt = 0; mt < MT; mt++)
          sumacc[mt] = __builtin_amdgcn_mfma_f32_16x16x32_bf16(af[mt], ones, sumacc[mt], 0, 0, 0);
    }
  }
#pragma unroll
  for (int mt = 0; mt < MT; mt++) {
    float sinv[4];
    if (ASUM) {
#pragma unroll
      for (int r = 0; r < 4; r++) sinv[r] = 1.f / sumacc[mt][r];
    }
#pragma unroll
    for (int nt = 0; nt < NT; nt++) {
      floatx4 v = acc[mt][nt];
#pragma unroll
      for (int r = 0; r < 4; r++) {
        int grow = m0 + wm + mt * 16 + q4 * 4 + r;
        int gcol = n0 + wn + nt * 16 + ml;
        float x = alpha * v[r];
        if (ASUM) x *= sinv[r];
        if (bias && kz == 0) x += bias[gcol];
        if (relu && !zone2) x = fmaxf(x, 0.f);
        if (expo) x = exp2f(x);  // alpha carries log2(e) fold
        if (OUT_BF16) {
          if (zone2)
            C2b[(size_t)grow * ldc2 + (gcol - ncut)] = f2b(x);
          else
            Cb[(size_t)grow * ldc + gcol] = f2b(x);
        } else {
          Cf[(size_t)grow * ldc + gcol] = x;
        }
      }
    }
  }
}

// --- xsad=norm(xA+xB); xsa=norm(xsa+0.05*xsad); write xsa fp32/bf16/bf16-T -----------
// xA+xB are the two split-K halves of (transition + updater + bias) + attention path.
// One-pass variance: var = (Sum(x^2) - E*mean^2)/(E-1); 2 reduction trees instead of 4.
__global__ void addnorm_kernel(const float* __restrict__ xA, const float* __restrict__ xB,
                               float* __restrict__ xsa, short* __restrict__ xsa_bf,
                               short* __restrict__ xsaT_bf, int E, int L) {
  int row = blockIdx.x, t = threadIdx.x;
  __shared__ float sdata[16];
  size_t off = (size_t)row * E + t;
  float s1 = xA[off] + xB[off];
  float2 r1 = block_sum2(s1, s1 * s1, sdata);
  float mean = r1.x / E;
  float var = fmaxf((r1.y - E * mean * mean) / (E - 1), 0.f);
  float n1 = s1 / (1.f + sqrtf(var));
  float t2 = xsa[off] + 0.05f * n1;
  float2 r2 = block_sum2(t2, t2 * t2, sdata);
  float mean2 = r2.x / E;
  float var2 = fmaxf((r2.y - E * mean2 * mean2) / (E - 1), 0.f);
  float res = t2 / (1.f + sqrtf(var2));
  xsa[off] = res;
  short b = f2b(res);
  xsa_bf[off] = b;
  int bb = row / L, l = row - bb * L;
  xsaT_bf[((size_t)bb * E + t) * L + l] = b;
}

// ---------------- gather masked positions (bf16) + targets ----------------
__global__ void gather_kernel(const float* __restrict__ xsa, const int* __restrict__ mask,
                              const int* __restrict__ unmasked,
                              short* __restrict__ lptok_bf, int* __restrict__ tgt,
                              int L, int LM, int E) {
  int bi = blockIdx.x;
  int b = bi / LM;
  int pos = mask[bi];
  float v = xsa[((size_t)b * L + pos) * E + threadIdx.x];
  lptok_bf[(size_t)bi * E + threadIdx.x] = f2b(v);
  if (threadIdx.x == 0) tgt[bi] = unmasked[b * L + pos];
}

// ---------------- head: MFMA logits + per-(row,128-chunk) max/sumexp ----------------
// v4: FULL K=256 Eb tile (128x256 = 64KB) staged in ONE shot (16 gl2lds16 all in
// flight) -> 1 barrier, then all 64 MFMA/wave with no further barriers. A (V-rows)
// from global/L2 inline. XCD-chunk-ownership; chunk-major stats.
__global__ __launch_bounds__(256) void head_stats_kernel(
    const short* __restrict__ V, const short* __restrict__ Eb,
    float* __restrict__ stM, float* __restrict__ stS, int Ksz, int nch, int Mrows) {
  int t0 = blockIdx.x;
  int xcd = t0 & 7, j = t0 >> 3;
  int c = ((j >> 4) << 3) | xcd;   // chunk; c%8 == t0%8 == XCD slot
  if (c >= nch) return;
  int m0 = (j & 15) * 64, n0 = c * 128;
  __shared__ short S[4 * 8192];  // 4 k-segs x (128 rows x 64 k) = 64KB, single buffer
  int tid = threadIdx.x, lane = tid & 63, w = tid >> 6;
  int wm = (w & 1) * 32, wn = (w >> 1) * 64;
  int ml = lane & 15, q4 = lane >> 4, sw = ml & 7;

  // stage ALL of Eb[n0:n0+128, 0:256] — 16 async loads, no intermediate barriers
#pragma unroll
  for (int i = 0; i < 16; i++) {
    int g = i * 256 + tid;          // 0..4095 16B-chunks
    int seg = g >> 10;              // k-segment (64 k each)
    int q = g & 1023;
    int n = q >> 3, cl = q & 7, cs = cl ^ (n & 7);
    gl2lds16(Eb + (size_t)(n0 + n) * Ksz + seg * 64 + cs * 8,
             &S[(i * 256 + w * 64) * 8]);
  }

  // A fragments (compiler may keep in regs or remat from L2 — no barrier pressure now)
  bf16x8 af[4][2][2];
#pragma unroll
  for (int mt = 0; mt < 2; mt++) {
    const short* vp = V + (size_t)(m0 + wm + mt * 16 + ml) * Ksz + q4 * 8;
#pragma unroll
    for (int kt = 0; kt < 4; kt++)
#pragma unroll
      for (int kk = 0; kk < 2; kk++)
        af[kt][kk][mt] = *reinterpret_cast<const bf16x8*>(vp + kt * 64 + kk * 32);
  }

  __syncthreads();  // whole tile resident
  floatx4 acc[2][4] = {};
#pragma unroll
  for (int t = 0; t < 4; t++) {
#pragma unroll
    for (int kk = 0; kk < 2; kk++) {
      int jj = kk * 4 + q4;
      bf16x8 bg[4];
#pragma unroll
      for (int nt = 0; nt < 4; nt++) {
        int r = wn + nt * 16 + ml;
        bg[nt] = *reinterpret_cast<const bf16x8*>(&S[t * 8192 + r * 64 + (jj ^ sw) * 8]);
      }
#pragma unroll
      for (int mt = 0; mt < 2; mt++)
#pragma unroll
        for (int nt = 0; nt < 4; nt++)
          acc[mt][nt] = __builtin_amdgcn_mfma_f32_16x16x32_bf16(af[t][kk][mt], bg[nt], acc[mt][nt], 0, 0, 0);
    }
  }
  __syncthreads();  // LDS reads done; reuse for reductions
  const float log2e = 1.4426950408889634f;
  float (*sred)[2] = (float (*)[2]) & S[0];
  float (*sred2)[2] = (float (*)[2]) & S[16384];
  float mx[2][4];
#pragma unroll
  for (int mt = 0; mt < 2; mt++)
#pragma unroll
    for (int r = 0; r < 4; r++)
      mx[mt][r] = fmaxf(fmaxf(acc[mt][0][r], acc[mt][1][r]), fmaxf(acc[mt][2][r], acc[mt][3][r]));
#pragma unroll
  for (int off = 1; off < 16; off <<= 1)
#pragma unroll
    for (int mt = 0; mt < 2; mt++)
#pragma unroll
      for (int r = 0; r < 4; r++) mx[mt][r] = fmaxf(mx[mt][r], __shfl_xor(mx[mt][r], off, 64));
  if (ml == 0)
#pragma unroll
    for (int mt = 0; mt < 2; mt++)
#pragma unroll
      for (int r = 0; r < 4; r++) sred[wm + mt * 16 + q4 * 4 + r][w >> 1] = mx[mt][r];
  __syncthreads();
  float sm[2][4];
#pragma unroll
  for (int mt = 0; mt < 2; mt++)
#pragma unroll
    for (int r = 0; r < 4; r++) {
      int row = wm + mt * 16 + q4 * 4 + r;
      float fm = fmaxf(sred[row][0], sred[row][1]);
      float s = 0.f;
#pragma unroll
      for (int nt = 0; nt < 4; nt++) s += exp2f((acc[mt][nt][r] - fm) * log2e);
      sm[mt][r] = s;
    }
#pragma unroll
  for (int off = 1; off < 16; off <<= 1)
#pragma unroll
    for (int mt = 0; mt < 2; mt++)
#pragma unroll
      for (int r = 0; r < 4; r++) sm[mt][r] += __shfl_xor(sm[mt][r], off, 64);
  if (ml == 0)
#pragma unroll
    for (int mt = 0; mt < 2; mt++)
#pragma unroll
      for (int r = 0; r < 4; r++) sred2[wm + mt * 16 + q4 * 4 + r][w >> 1] = sm[mt][r];
  __syncthreads();
  if (tid < 64) {
    float fm = fmaxf(sred[tid][0], sred[tid][1]);
    stM[(size_t)c * Mrows + m0 + tid] = fm;
    stS[(size_t)c * Mrows + m0 + tid] = sred2[tid][0] + sred2[tid][1];
  }
}

// -------- merged: lse per row (chunk-major stats) + logit at target ----------
__global__ void lse_logit_kernel(const float* __restrict__ statsM,
                                 const float* __restrict__ statsS,
                                 const short* __restrict__ V, const short* __restrict__ Eb,
                                 const int* __restrict__ tgt,
                                 float* __restrict__ lse, float* __restrict__ lt,
                                 int nch, int Mrows, int E, int Nn, int KN, int LM) {
  int row = blockIdx.x, t = threadIdx.x;
  // target logit: dot(vv[row], Eb[g]) across E threads
  int b = row / Nn;
  int i = (row - b * Nn) / KN;
  int g = tgt[b * LM + i];
  float v = b2f(V[(size_t)row * E + t]) * b2f(Eb[(size_t)g * E + t]);
  // lse chunk scan
  float m = -INFINITY, s = 0.f;
  for (int c = t; c < nch; c += blockDim.x) {
    float cm = statsM[(size_t)c * Mrows + row];
    float cs = statsS[(size_t)c * Mrows + row];
    float M = fmaxf(m, cm);
    s = s * expf(m - M) + cs * expf(cm - M);
    m = M;
  }
  __shared__ float sm[256], ss[256], sd[8];
  float dot = block_sum(v, sd);
  if (t == 0) lt[row] = dot;
  sm[t] = m;
  ss[t] = s;
  __syncthreads();
  for (int o = 128; o > 0; o >>= 1) {
    if (t < o) {
      float m2 = sm[t + o], s2 = ss[t + o];
      float M = fmaxf(sm[t], m2);
      float sc = ss[t] * expf(sm[t] - M) + s2 * expf(m2 - M);
      sm[t] = M;
      ss[t] = sc;
    }
    __syncthreads();
  }
  if (t == 0) lse[row] = sm[0] + logf(ss[0]);
}

// ---------------- final ----------------
__global__ void final_kernel(const float* __restrict__ lt, const float* __restrict__ lse,
                             float* __restrict__ out, int LM, int KN) {
  int b = blockIdx.x, i = threadIdx.x;
  int base = (b * LM + i) * KN;
  float m = -INFINITY;
  for (int k = 0; k < KN; k++) m = fmaxf(m, lt[base + k] - lse[base + k]);
  float s = 0.f;
  for (int k = 0; k < KN; k++) s += expf(lt[base + k] - lse[base + k] - m);
  float cent = m + logf(s) - logf((float)KN);
#pragma unroll
  for (int o = 32; o > 0; o >>= 1) cent += __shfl_down(cent, o, 64);
  if (i == 0) out[b] = -cent / LM;
}

// ---------------- host dispatchers ----------------
// cfg: 0 = 128x128, 1 = 128x64, 2 = 64x64
static inline void bgemm(hipStream_t st, int cfg, const short* A, int lda, long sA,
                         const short* B, int ldb, long sB,
                         void* C, int ldc, long sC, int M, int N, int Ksz, int nb,
                         float alpha, const float* bias, int relu, int out_bf16,
                         int shiftA, int shiftB, int ns1, int ns2, int Lroll,
                         int expo = 0, int asum = 0,
                         short* C2 = nullptr, int ldc2 = 0, int ncut = 0,
                         int ksplit = 1, long ksC = 0) {
  dim3 block(256);
  int nz = nb * ksplit;
#define BG_ARGS A, lda, sA, B, ldb, sB, C, ldc, sC, C2, ldc2, ncut, Ksz, alpha, bias, relu, expo, shiftA, shiftB, ns1, ns2, Lroll, ksplit, ksC
  if (cfg == 0) {
    dim3 grid(N / 128, M / 128, nz);
    if (out_bf16)
      bgemm_kernel<128, 128, 1, 0><<<grid, block, 0, st>>>(BG_ARGS);
    else
      bgemm_kernel<128, 128, 0, 0><<<grid, block, 0, st>>>(BG_ARGS);
  } else if (cfg == 1) {
    dim3 grid(N / 64, M / 128, nz);
    if (out_bf16) {
      if (asum)
        bgemm_kernel<128, 64, 1, 1><<<grid, block, 0, st>>>(BG_ARGS);
      else
        bgemm_kernel<128, 64, 1, 0><<<grid, block, 0, st>>>(BG_ARGS);
    } else {
      bgemm_kernel<128, 64, 0, 0><<<grid, block, 0, st>>>(BG_ARGS);
    }
  } else {
    dim3 grid(N / 64, M / 64, nz);
    if (out_bf16)
      bgemm_kernel<64, 64, 1, 0><<<grid, block, 0, st>>>(BG_ARGS);
    else
      bgemm_kernel<64, 64, 0, 0><<<grid, block, 0, st>>>(BG_ARGS);
  }
#undef BG_ARGS
}

static inline void cvt(hipStream_t st, const float* src, short* dst, long n) {
  long n4 = n / 4;
  cvt_kernel<<<(int)((n4 + 255) / 256), 256, 0, st>>>(src, dst, n4);
}

static inline void cvt2(hipStream_t st, const float* src, short* dst, int R, int C,
                        int ldS, int ldD, long sS, long sD, int nb) {
  dim3 grid(C / 32, R / 32, nb), block(32, 8);
  cvt2_kernel<<<grid, block, 0, st>>>(src, dst, ldS, ldD, sS, sD);
}

static inline void cvtT2(hipStream_t st, const float* src, short* dst, int R, int C,
                         int ldS, int ldD, long sS, long sD, int nb) {
  dim3 grid(C / 32, R / 32, nb), block(32, 8);
  cvtT2_kernel<<<grid, block, 0, st>>>(src, dst, ldS, ldD, sS, sD);
}

extern "C" void kernel_launch(void* const* d_in, const int* in_sizes, int n_in,
                              void* d_out, int out_size, void* d_ws, size_t ws_size,
                              hipStream_t stream) {
  const int* masked = (const int*)d_in[0];
  const int* unmasked = (const int*)d_in[1];
  const int* mask = (const int*)d_in[2];
  const float* embed = (const float*)d_in[3];
  const float* Wt = (const float*)d_in[4];
  const float* bt = (const float*)d_in[5];
  const float* Wtc = (const float*)d_in[6];
  const float* Wq = (const float*)d_in[7];
  const float* Wd = (const float*)d_in[8];
  const float* Wo = (const float*)d_in[9];
  const float* Wu = (const float*)d_in[10];
  const float* Wem = (const float*)d_in[11];
  const float* Wkc = (const float*)d_in[12];
  const float* bkc = (const float*)d_in[13];

  const int B = out_size;                  // 4
  const int BL = in_sizes[0];              // 2048
  const int L = BL / B;                    // 512
  const int BLM = in_sizes[2];             // 256
  const int LM = BLM / B;                  // 64
  const int E = in_sizes[4] / in_sizes[5]; // 256
  const int D = in_sizes[5] / E;           // 6
  const int G = in_sizes[3] / E;           // 32000
  const int K = in_sizes[7] / (D * E * E); // 8
  const int KN = in_sizes[12] / (E * E);   // 4
  const int KE = K * E;                    // 2048
  const int N = LM * KN;                   // 256
  const float inv_sqrt_e = 1.0f / sqrtf((float)E);
  const int nch = G / 128;                 // 250
  const int E3 = 3 * E;                    // 768
  const int KA = E3 + KE;                  // 2816 = [t1a|t1b|z|r] concat-K width
  const int NQ = 2 * E + KE;               // 2560 = merged catA1+q output width

  // ---- workspace carve ----
  char* base = (char*)d_ws;
  size_t off = 0;
  auto carve = [&](size_t bytes) {
    char* p = base + off;
    off += (bytes + 255) & ~(size_t)255;
    return p;
  };
  float* xsa = (float*)carve((size_t)BL * E * 4);
  float* xsad = (float*)carve((size_t)2 * BL * E * 4);     // 2 split-K halves
  float* stM = (float*)carve((size_t)B * N * nch * 4);
  float* stS = (float*)carve((size_t)B * N * nch * 4);
  float* lse = (float*)carve((size_t)B * N * 4);
  float* lt = (float*)carve((size_t)B * N * 4);
  int* tgt = (int*)carve((size_t)B * LM * 4);
  short* xsa_bf = (short*)carve((size_t)BL * E * 2);
  short* xsaT_bf = (short*)carve((size_t)B * E * L * 2);
  short* catA = (short*)carve((size_t)BL * KA * 2);        // [t1a|t1b|z|r], ld KA
  short* qy_bf = (short*)carve((size_t)BL * KE * 2);
  short* hP_bf = (short*)carve((size_t)B * L * K * L * 2); // exp'd attention scores
  short* wd_all = (short*)carve((size_t)D * KE * KE * 2);
  short* BcatQ = (short*)carve((size_t)D * NQ * E * 2);    // [wtT; wtc; Wq] rows, ld E
  short* Bcat2x = (short*)carve((size_t)D * E * KA * 2);   // [wtcT|wt|wu|woT], ld KA
  short* embed_bf = (short*)carve((size_t)G * E * 2);
  short* WemT_bf = (short*)carve((size_t)E * E * 2);
  short* Wkc_bf = (short*)carve((size_t)KN * E * E * 2);
  short* gram_bf = (short*)carve((size_t)B * E * E * 2);
  short* xx_bf = (short*)carve((size_t)B * N * E * 2);
  short* xx2_bf = (short*)carve((size_t)B * N * E * 2);
  short* vv_bf = (short*)carve((size_t)B * N * E * 2);
  short* lptok_bf = (short*)carve((size_t)BLM * E * 2);

  // ---- up-front conversions ----
  cvt(stream, embed, embed_bf, (long)G * E);
  cvt(stream, Wd, wd_all, (long)D * KE * KE);
  cvt(stream, Wkc, Wkc_bf, (long)KN * E * E);
  cvtT2(stream, Wem, WemT_bf, E, E, E, E, 0, 0, 1);
  // BcatQ rows: [0,E)=wtT, [E,2E)=wtc, [2E,2E+KE)=Wq  (all NT B-operands, ld E)
  cvtT2(stream, Wt, BcatQ, E, E, E, E, (long)E * E, (long)NQ * E, D);
  cvt2(stream, Wtc, BcatQ + (size_t)E * E, E, E, E, E, (long)E * E, (long)NQ * E, D);
  cvt2(stream, Wq, BcatQ + (size_t)2 * E * E, KE, E, E, E, (long)KE * E, (long)NQ * E, D);
  // Bcat2x = [wtcT | wt | wu | woT], ld KA (NT B for catA @ [wtc; wtT; wuT; wo])
  cvtT2(stream, Wtc, Bcat2x, E, E, E, KA, (long)E * E, (long)E * KA, D);
  cvt2(stream, Wt, Bcat2x + E, E, E, E, KA, (long)E * E, (long)E * KA, D);
  cvt2(stream, Wu, Bcat2x + 2 * E, E, E, E, KA, (long)E * E, (long)E * KA, D);
  cvtT2(stream, Wo, Bcat2x + E3, KE, E, E, KA, (long)KE * E, (long)E * KA, D);

  // z = norm(embed[masked]); xsa = z (+bf16, +transposed, +catA z-slot)
  embed_norm_kernel<<<BL, E, 0, stream>>>(masked, embed, xsa, xsa_bf, xsaT_bf, catA,
                                          E, L, KA, 2 * E);

  const float log2e = 1.4426950408889634f;
  for (int d = 0; d < D; d++) {
    const float* btl = bt + (size_t)d * E;
    // merged: catA[:,0:512] = [relu(roll(xsa,+1)@wt) | relu(roll(xsa,-1)@wtcT)]
    //         qy            = xsa @ wq^T              (cols 512..2559, no relu)
    bgemm(stream, 1, xsa_bf, E, 0, BcatQ + (size_t)d * NQ * E, E, 0,
          catA, KA, 0, BL, NQ, E, 1, 1.f, nullptr, 1, 1,
          -1, +1, E, 2 * E, L, 0, 0, qy_bf, KE, 2 * E);
    // hP = exp(q . xsa^T / sqrt(E)) via exp2(alpha*h), alpha = log2e/sqrt(E)
    bgemm(stream, 0, qy_bf, E, (long)L * KE, xsa_bf, E, (long)L * E,
          hP_bf, L, (long)L * K * L, L * K, L, E, B, inv_sqrt_e * log2e, nullptr, 0, 1,
          0, 0, 0, 0, L, 1);
    // y = (P @ xsa) / rowsum(P)  — softmax normalization fused via ones-MFMA row sums
    bgemm(stream, 1, hP_bf, L, (long)L * K * L, xsaT_bf, L, (long)E * L,
          qy_bf, E, (long)L * KE, L * K, E, L, B, 1.f, nullptr, 0, 1,
          0, 0, 0, 0, L, 0, 1);
    // catA[:,768:2816] = r = relu(y @ wd^T)  (128x128 tile: 256 blocks, 1/CU)
    bgemm(stream, 0, qy_bf, KE, 0, wd_all + (size_t)d * KE * KE, KE, 0,
          catA + E3, KA, 0, BL, KE, KE, 1, 1.f, nullptr, 1, 1, 0, 0, 0, 0, L);
    // xsadt = catA @ [wtc; wtT; wuT; wo] + bt, split-K=2 into xsad[0],xsad[BL*E]
    bgemm(stream, 2, catA, KA, 0, Bcat2x + (size_t)d * E * KA, KA, 0,
          xsad, E, 0, BL, E, KA, 1, 1.f, btl, 0, 0, 0, 0, 0, 0, L,
          0, 0, nullptr, 0, 0, 2, (long)BL * E);
    addnorm_kernel<<<BL, E, 0, stream>>>(xsad, xsad + (size_t)BL * E,
                                         xsa, xsa_bf, xsaT_bf, E, L);
  }

  // ---- head ----
  gather_kernel<<<BLM, E, 0, stream>>>(xsa, mask, unmasked, lptok_bf, tgt, L, LM, E);
  bgemm(stream, 2, xsaT_bf, L, (long)E * L, xsaT_bf, L, (long)E * L,
        gram_bf, E, (long)E * E, E, E, L, B, 1.f, nullptr, 0, 1, 0, 0, 0, 0, L);
  bgemm(stream, 2, lptok_bf, E, 0, Wkc_bf, E, 0, xx_bf, KN * E, 0, BLM, KN * E, E, 1,
        1.f, bkc, 0, 1, 0, 0, 0, 0, L);
  bgemm(stream, 2, xx_bf, E, (long)N * E, gram_bf, E, (long)E * E,
        xx2_bf, E, (long)N * E, N, E, E, B, 1.f, nullptr, 0, 1, 0, 0, 0, 0, L);
  bgemm(stream, 2, xx2_bf, E, 0, WemT_bf, E, 0, vv_bf, E, 0, B * N, E, E, 1,
        1.f, nullptr, 0, 1, 0, 0, 0, 0, L);
  {
    int nchPad = (nch + 7) & ~7;  // 256
    head_stats_kernel<<<nchPad * 16, 256, 0, stream>>>(vv_bf, embed_bf, stM, stS,
                                                       E, nch, B * N);
  }
  lse_logit_kernel<<<B * N, 256, 0, stream>>>(stM, stS, vv_bf, embed_bf, tgt,
                                              lse, lt, nch, B * N, E, N, KN, LM);
  final_kernel<<<B, LM, 0, stream>>>(lt, lse, (float*)d_out, LM, KN);
}

// Round 10
// 871.647 us; speedup vs baseline: 1.0389x; 1.0389x over previous
//
#include <hip/hip_runtime.h>
#include <hip/hip_bf16.h>
#include <math.h>

typedef __bf16 bf16x8 __attribute__((ext_vector_type(8)));
typedef float floatx4 __attribute__((ext_vector_type(4)));

__device__ __forceinline__ short f2b(float f) {
  __hip_bfloat16 h = __float2bfloat16(f);
  return *reinterpret_cast<short*>(&h);
}
__device__ __forceinline__ float b2f(short s) {
  unsigned u = ((unsigned)(unsigned short)s) << 16;
  float f;
  __builtin_memcpy(&f, &u, 4);
  return f;
}

// async global->LDS, 16B per lane; lds base must be wave-uniform
__device__ __forceinline__ void gl2lds16(const void* g, void* l) {
  __builtin_amdgcn_global_load_lds((__attribute__((address_space(1))) const void*)g,
                                   (__attribute__((address_space(3))) void*)l, 16, 0, 0);
}

// ---------------- block reduction helpers ----------------
__device__ __forceinline__ float block_sum(float v, float* sdata) {
#pragma unroll
  for (int o = 32; o > 0; o >>= 1) v += __shfl_down(v, o, 64);
  __syncthreads();
  int lane = threadIdx.x & 63, wid = threadIdx.x >> 6;
  if (lane == 0) sdata[wid] = v;
  __syncthreads();
  float s = 0.f;
  int nw = blockDim.x >> 6;
  for (int i = 0; i < nw; i++) s += sdata[i];
  return s;
}

// fused two-value block sum (one barrier pair for both)
__device__ __forceinline__ float2 block_sum2(float a, float b, float* sdata) {
#pragma unroll
  for (int o = 32; o > 0; o >>= 1) {
    a += __shfl_down(a, o, 64);
    b += __shfl_down(b, o, 64);
  }
  __syncthreads();
  int lane = threadIdx.x & 63, wid = threadIdx.x >> 6;
  if (lane == 0) { sdata[wid] = a; sdata[8 + wid] = b; }
  __syncthreads();
  float sa = 0.f, sb = 0.f;
  int nw = blockDim.x >> 6;
  for (int i = 0; i < nw; i++) { sa += sdata[i]; sb += sdata[8 + i]; }
  return make_float2(sa, sb);
}

// ---------------- conversion kernels ----------------
__global__ void cvt_kernel(const float* __restrict__ src, short* __restrict__ dst, long n4) {
  long i = (long)blockIdx.x * blockDim.x + threadIdx.x;
  if (i < n4) {
    float4 v = ((const float4*)src)[i];
    short4 o;
    o.x = f2b(v.x); o.y = f2b(v.y); o.z = f2b(v.z); o.w = f2b(v.w);
    ((short4*)dst)[i] = o;
  }
}

// dst[r*ldD + c] = bf16(src[r*ldS + c]); grid (C/32, R/32, nb), block (32,8)
__global__ void cvt2_kernel(const float* __restrict__ src, short* __restrict__ dst,
                            int ldS, int ldD, long sS, long sD) {
  src += (size_t)blockIdx.z * sS;
  dst += (size_t)blockIdx.z * sD;
  int c = blockIdx.x * 32 + threadIdx.x;
  int r0 = blockIdx.y * 32 + threadIdx.y;
#pragma unroll
  for (int i = 0; i < 32; i += 8)
    dst[(size_t)(r0 + i) * ldD + c] = f2b(src[(size_t)(r0 + i) * ldS + c]);
}

// dst[c*ldD + r] = bf16(src[r*ldS + c]); grid (C/32, R/32, nb), block (32,8)
__global__ void cvtT2_kernel(const float* __restrict__ src, short* __restrict__ dst,
                             int ldS, int ldD, long sS, long sD) {
  src += (size_t)blockIdx.z * sS;
  dst += (size_t)blockIdx.z * sD;
  __shared__ float tile[32][33];
  int r0 = blockIdx.y * 32, c0 = blockIdx.x * 32;
  int tx = threadIdx.x, ty = threadIdx.y;
#pragma unroll
  for (int i = 0; i < 32; i += 8)
    tile[ty + i][tx] = src[(size_t)(r0 + ty + i) * ldS + c0 + tx];
  __syncthreads();
#pragma unroll
  for (int i = 0; i < 32; i += 8)
    dst[(size_t)(c0 + ty + i) * ldD + r0 + tx] = f2b(tile[tx][ty + i]);
}

// ---------------- embed gather + norm; fills xsa, xsa_bf, xsaT_bf, z-slot of catA -----
__global__ void embed_norm_kernel(const int* __restrict__ masked,
                                  const float* __restrict__ embed,
                                  float* __restrict__ xsa, short* __restrict__ xsa_bf,
                                  short* __restrict__ xsaT_bf, short* __restrict__ catA,
                                  int E, int L, int ldA, int zoff) {
  int row = blockIdx.x;
  int g = masked[row];
  __shared__ float sdata[16];
  float x = embed[(size_t)g * E + threadIdx.x];
  float2 ss = block_sum2(x, x * x, sdata);
  float mean = ss.x / E;
  float var = fmaxf((ss.y - E * mean * mean) / (E - 1), 0.f);
  float val = x / (1.0f + sqrtf(var));
  size_t off = (size_t)row * E + threadIdx.x;
  xsa[off] = val;
  short b = f2b(val);
  xsa_bf[off] = b;
  catA[(size_t)row * ldA + zoff + threadIdx.x] = b;
  int bb = row / L, l = row - bb * L;
  xsaT_bf[((size_t)bb * E + threadIdx.x) * L + l] = b;
}

// ---------------- bf16 MFMA GEMM (NT), async dbuf, XOR swizzle, tiled ----------------
// C[m,n] = alpha*sum_k A[m,k]*B[n,k] [*1/rowsum] [+bias[n]] [relu] [exp2];
// BMxBN tile, BK=64, 4 waves 2x2.
// A-row roll (3 zones): shift = n0<ns1 ? shiftA : (n0<ns2 ? shiftB : 0), per Lroll rows.
// Dual output: if C2b && n0>=ncut, write bf16 to C2b at col gcol-ncut (no relu).
// ASUM: accumulate per-A-row sums via MFMA with ones-B; epilogue multiplies by 1/sum.
// ksplit: grid.z = nb*ksplit; K-slice kz handles K-range [kz*K/ksplit, ...); fp32 C
//         written to Cf + kz*ksC (caller sums the slices); bias applied only by kz==0.
template <int BM, int BN, int OUT_BF16, int ASUM>
__global__ __launch_bounds__(256) void bgemm_kernel(
    const short* __restrict__ A, int lda, long sA,
    const short* __restrict__ B, int ldb, long sB,
    void* __restrict__ Cv, int ldc, long sC,
    short* __restrict__ C2b, int ldc2, int ncut,
    int Ksz, float alpha, const float* __restrict__ bias,
    int relu, int expo, int shiftA, int shiftB, int ns1, int ns2, int Lroll,
    int ksplit, long ksC) {
  constexpr int WM = BM / 2, WN = BN / 2;
  constexpr int MT = WM / 16, NT = WN / 16;
  constexpr int NCH = (BM + BN) * 8;  // 16B chunks per K-tile
  constexpr int LPT = NCH / 256;      // chunk-groups per thread
  int bz = blockIdx.z, kz = 0;
  if (ksplit > 1) {
    bz = blockIdx.z / ksplit;
    kz = blockIdx.z - bz * ksplit;
  }
  int Kper = Ksz / ksplit;
  int koff = kz * Kper;
  A += (size_t)bz * sA + koff;
  B += (size_t)bz * sB + koff;
  float* Cf = (float*)Cv + (size_t)bz * sC + (size_t)kz * ksC;
  short* Cb = (short*)Cv + (size_t)bz * sC;
  int m0 = blockIdx.y * BM, n0 = blockIdx.x * BN;
  int shift = (n0 < ns1) ? shiftA : ((n0 < ns2) ? shiftB : 0);
  int zone2 = (C2b != nullptr) && (n0 >= ncut);
  __shared__ short S[2][(BM + BN) * 64];
  int tid = threadIdx.x, lane = tid & 63, w = tid >> 6;
  int wm = (w & 1) * WM, wn = (w >> 1) * WN;
  int ml = lane & 15, q4 = lane >> 4, sw = ml & 7;

  const short* src[LPT];
#pragma unroll
  for (int i = 0; i < LPT; i++) {
    int q = i * 256 + w * 64 + lane;
    if (q < BM * 8) {
      int m = q >> 3, cl = q & 7, cs = cl ^ (m & 7);
      int mg = m0 + m;
      if (shift != 0) {
        int bb = mg / Lroll, l = mg - bb * Lroll;
        l = (l + shift + Lroll) % Lroll;
        mg = bb * Lroll + l;
      }
      src[i] = A + (size_t)mg * lda + cs * 8;
    } else {
      int qb = q - BM * 8;
      int n = qb >> 3, cl = qb & 7, cs = cl ^ (n & 7);
      src[i] = B + (size_t)(n0 + n) * ldb + cs * 8;
    }
  }
  // prologue: stage tile 0
#pragma unroll
  for (int i = 0; i < LPT; i++)
    gl2lds16(src[i], &S[0][(i * 256 + w * 64) * 8]);
  floatx4 acc[MT][NT] = {};
  floatx4 sumacc[ASUM ? MT : 1] = {};
  bf16x8 ones;
#pragma unroll
  for (int i = 0; i < 8; i++) ones[i] = (__bf16)1.0f;
  int nT = Kper >> 6;
  for (int t = 0; t < nT; t++) {
    __syncthreads();  // drains vmcnt: tile t resident; all waves done with t-1
    int cur = t & 1;
    if (t + 1 < nT) {
      int nxt = cur ^ 1, ko = (t + 1) * 64;
#pragma unroll
      for (int i = 0; i < LPT; i++)
        gl2lds16(src[i] + ko, &S[nxt][(i * 256 + w * 64) * 8]);
    }
#pragma unroll
    for (int kk = 0; kk < 2; kk++) {
      int j = kk * 4 + q4;
      bf16x8 af[MT], bg[NT];
#pragma unroll
      for (int mt = 0; mt < MT; mt++) {
        int r = wm + mt * 16 + ml;
        af[mt] = *reinterpret_cast<const bf16x8*>(&S[cur][r * 64 + (j ^ sw) * 8]);
      }
#pragma unroll
      for (int nt = 0; nt < NT; nt++) {
        int r = wn + nt * 16 + ml;
        bg[nt] = *reinterpret_cast<const bf16x8*>(&S[cur][BM * 64 + r * 64 + (j ^ sw) * 8]);
      }
#pragma unroll
      for (int mt = 0; mt < MT; mt++)
#pragma unroll
        for (int nt = 0; nt < NT; nt++)
          acc[mt][nt] = __builtin_amdgcn_mfma_f32_16x16x32_bf16(af[mt], bg[nt], acc[mt][nt], 0, 0, 0);
      if (ASUM)
#pragma unroll
        for (int mt = 0; mt < MT; mt++)
          sumacc[mt] = __builtin_amdgcn_mfma_f32_16x16x32_bf16(af[mt], ones, sumacc[mt], 0, 0, 0);
    }
  }
#pragma unroll
  for (int mt = 0; mt < MT; mt++) {
    float sinv[4];
    if (ASUM) {
#pragma unroll
      for (int r = 0; r < 4; r++) sinv[r] = 1.f / sumacc[mt][r];
    }
#pragma unroll
    for (int nt = 0; nt < NT; nt++) {
      floatx4 v = acc[mt][nt];
#pragma unroll
      for (int r = 0; r < 4; r++) {
        int grow = m0 + wm + mt * 16 + q4 * 4 + r;
        int gcol = n0 + wn + nt * 16 + ml;
        float x = alpha * v[r];
        if (ASUM) x *= sinv[r];
        if (bias && kz == 0) x += bias[gcol];
        if (relu && !zone2) x = fmaxf(x, 0.f);
        if (expo) x = exp2f(x);  // alpha carries log2(e) fold
        if (OUT_BF16) {
          if (zone2)
            C2b[(size_t)grow * ldc2 + (gcol - ncut)] = f2b(x);
          else
            Cb[(size_t)grow * ldc + gcol] = f2b(x);
        } else {
          Cf[(size_t)grow * ldc + gcol] = x;
        }
      }
    }
  }
}

// --- xsad=norm(xA+xB); xsa=norm(xsa+0.05*xsad); write xsa fp32/bf16/bf16-T -----------
// xA+xB are the two split-K halves of (transition + updater + bias) + attention path.
// One-pass variance: var = (Sum(x^2) - E*mean^2)/(E-1); 2 reduction trees instead of 4.
__global__ void addnorm_kernel(const float* __restrict__ xA, const float* __restrict__ xB,
                               float* __restrict__ xsa, short* __restrict__ xsa_bf,
                               short* __restrict__ xsaT_bf, int E, int L) {
  int row = blockIdx.x, t = threadIdx.x;
  __shared__ float sdata[16];
  size_t off = (size_t)row * E + t;
  float s1 = xA[off] + xB[off];
  float2 r1 = block_sum2(s1, s1 * s1, sdata);
  float mean = r1.x / E;
  float var = fmaxf((r1.y - E * mean * mean) / (E - 1), 0.f);
  float n1 = s1 / (1.f + sqrtf(var));
  float t2 = xsa[off] + 0.05f * n1;
  float2 r2 = block_sum2(t2, t2 * t2, sdata);
  float mean2 = r2.x / E;
  float var2 = fmaxf((r2.y - E * mean2 * mean2) / (E - 1), 0.f);
  float res = t2 / (1.f + sqrtf(var2));
  xsa[off] = res;
  short b = f2b(res);
  xsa_bf[off] = b;
  int bb = row / L, l = row - bb * L;
  xsaT_bf[((size_t)bb * E + t) * L + l] = b;
}

// ---------------- gather masked positions (bf16) + targets ----------------
__global__ void gather_kernel(const float* __restrict__ xsa, const int* __restrict__ mask,
                              const int* __restrict__ unmasked,
                              short* __restrict__ lptok_bf, int* __restrict__ tgt,
                              int L, int LM, int E) {
  int bi = blockIdx.x;
  int b = bi / LM;
  int pos = mask[bi];
  float v = xsa[((size_t)b * L + pos) * E + threadIdx.x];
  lptok_bf[(size_t)bi * E + threadIdx.x] = f2b(v);
  if (threadIdx.x == 0) tgt[bi] = unmasked[b * L + pos];
}

// ---------------- head: MFMA logits + per-(row,128-chunk) max/sumexp ----------------
// v3 (best measured): A (V-rows) fragments hoisted pre-loop; LDS stages Eb only
// (128x64 dbuf = 32KB). XCD-chunk-ownership; chunk-major stats.
__global__ __launch_bounds__(256) void head_stats_kernel(
    const short* __restrict__ V, const short* __restrict__ Eb,
    float* __restrict__ stM, float* __restrict__ stS, int Ksz, int nch, int Mrows) {
  int t0 = blockIdx.x;
  int xcd = t0 & 7, j = t0 >> 3;
  int c = ((j >> 4) << 3) | xcd;   // chunk; c%8 == t0%8 == XCD slot
  if (c >= nch) return;
  int m0 = (j & 15) * 64, n0 = c * 128;
  __shared__ short S[2][128 * 64];  // Eb only, dbuf = 32KB
  int tid = threadIdx.x, lane = tid & 63, w = tid >> 6;
  int wm = (w & 1) * 32, wn = (w >> 1) * 64;
  int ml = lane & 15, q4 = lane >> 4, sw = ml & 7;

  // Hoist A fragments for all K (Ksz == 256 for this problem): af[kt][kk][mt]
  bf16x8 af[4][2][2];
#pragma unroll
  for (int mt = 0; mt < 2; mt++) {
    const short* vp = V + (size_t)(m0 + wm + mt * 16 + ml) * Ksz + q4 * 8;
#pragma unroll
    for (int kt = 0; kt < 4; kt++)
#pragma unroll
      for (int kk = 0; kk < 2; kk++)
        af[kt][kk][mt] = *reinterpret_cast<const bf16x8*>(vp + kt * 64 + kk * 32);
  }

  const short* src[4];
#pragma unroll
  for (int i = 0; i < 4; i++) {
    int q = i * 256 + w * 64 + lane;
    int n = q >> 3, cl = q & 7, cs = cl ^ (n & 7);
    src[i] = Eb + (size_t)(n0 + n) * Ksz + cs * 8;
  }
#pragma unroll
  for (int i = 0; i < 4; i++)
    gl2lds16(src[i], &S[0][(i * 256 + w * 64) * 8]);
  floatx4 acc[2][4] = {};
#pragma unroll
  for (int t = 0; t < 4; t++) {  // Ksz/64 == 4, static for af indexing
    __syncthreads();
    int cur = t & 1;
    if (t + 1 < 4) {
      int nxt = cur ^ 1, ko = (t + 1) * 64;
#pragma unroll
      for (int i = 0; i < 4; i++)
        gl2lds16(src[i] + ko, &S[nxt][(i * 256 + w * 64) * 8]);
    }
#pragma unroll
    for (int kk = 0; kk < 2; kk++) {
      int jj = kk * 4 + q4;
      bf16x8 bg[4];
#pragma unroll
      for (int nt = 0; nt < 4; nt++) {
        int r = wn + nt * 16 + ml;
        bg[nt] = *reinterpret_cast<const bf16x8*>(&S[cur][r * 64 + (jj ^ sw) * 8]);
      }
#pragma unroll
      for (int mt = 0; mt < 2; mt++)
#pragma unroll
        for (int nt = 0; nt < 4; nt++)
          acc[mt][nt] = __builtin_amdgcn_mfma_f32_16x16x32_bf16(af[t][kk][mt], bg[nt], acc[mt][nt], 0, 0, 0);
    }
  }
  __syncthreads();
  const float log2e = 1.4426950408889634f;
  float (*sred)[2] = (float (*)[2]) & S[0][0];
  float (*sred2)[2] = (float (*)[2]) & S[1][0];
  float mx[2][4];
#pragma unroll
  for (int mt = 0; mt < 2; mt++)
#pragma unroll
    for (int r = 0; r < 4; r++)
      mx[mt][r] = fmaxf(fmaxf(acc[mt][0][r], acc[mt][1][r]), fmaxf(acc[mt][2][r], acc[mt][3][r]));
#pragma unroll
  for (int off = 1; off < 16; off <<= 1)
#pragma unroll
    for (int mt = 0; mt < 2; mt++)
#pragma unroll
      for (int r = 0; r < 4; r++) mx[mt][r] = fmaxf(mx[mt][r], __shfl_xor(mx[mt][r], off, 64));
  if (ml == 0)
#pragma unroll
    for (int mt = 0; mt < 2; mt++)
#pragma unroll
      for (int r = 0; r < 4; r++) sred[wm + mt * 16 + q4 * 4 + r][w >> 1] = mx[mt][r];
  __syncthreads();
  float sm[2][4];
#pragma unroll
  for (int mt = 0; mt < 2; mt++)
#pragma unroll
    for (int r = 0; r < 4; r++) {
      int row = wm + mt * 16 + q4 * 4 + r;
      float fm = fmaxf(sred[row][0], sred[row][1]);
      float s = 0.f;
#pragma unroll
      for (int nt = 0; nt < 4; nt++) s += exp2f((acc[mt][nt][r] - fm) * log2e);
      sm[mt][r] = s;
    }
#pragma unroll
  for (int off = 1; off < 16; off <<= 1)
#pragma unroll
    for (int mt = 0; mt < 2; mt++)
#pragma unroll
      for (int r = 0; r < 4; r++) sm[mt][r] += __shfl_xor(sm[mt][r], off, 64);
  if (ml == 0)
#pragma unroll
    for (int mt = 0; mt < 2; mt++)
#pragma unroll
      for (int r = 0; r < 4; r++) sred2[wm + mt * 16 + q4 * 4 + r][w >> 1] = sm[mt][r];
  __syncthreads();
  if (tid < 64) {
    float fm = fmaxf(sred[tid][0], sred[tid][1]);
    stM[(size_t)c * Mrows + m0 + tid] = fm;
    stS[(size_t)c * Mrows + m0 + tid] = sred2[tid][0] + sred2[tid][1];
  }
}

// -------- merged: lse per row (chunk-major stats) + logit at target ----------
__global__ void lse_logit_kernel(const float* __restrict__ statsM,
                                 const float* __restrict__ statsS,
                                 const short* __restrict__ V, const short* __restrict__ Eb,
                                 const int* __restrict__ tgt,
                                 float* __restrict__ lse, float* __restrict__ lt,
                                 int nch, int Mrows, int E, int Nn, int KN, int LM) {
  int row = blockIdx.x, t = threadIdx.x;
  // target logit: dot(vv[row], Eb[g]) across E threads
  int b = row / Nn;
  int i = (row - b * Nn) / KN;
  int g = tgt[b * LM + i];
  float v = b2f(V[(size_t)row * E + t]) * b2f(Eb[(size_t)g * E + t]);
  // lse chunk scan
  float m = -INFINITY, s = 0.f;
  for (int c = t; c < nch; c += blockDim.x) {
    float cm = statsM[(size_t)c * Mrows + row];
    float cs = statsS[(size_t)c * Mrows + row];
    float M = fmaxf(m, cm);
    s = s * expf(m - M) + cs * expf(cm - M);
    m = M;
  }
  __shared__ float sm[256], ss[256], sd[8];
  float dot = block_sum(v, sd);
  if (t == 0) lt[row] = dot;
  sm[t] = m;
  ss[t] = s;
  __syncthreads();
  for (int o = 128; o > 0; o >>= 1) {
    if (t < o) {
      float m2 = sm[t + o], s2 = ss[t + o];
      float M = fmaxf(sm[t], m2);
      float sc = ss[t] * expf(sm[t] - M) + s2 * expf(m2 - M);
      sm[t] = M;
      ss[t] = sc;
    }
    __syncthreads();
  }
  if (t == 0) lse[row] = sm[0] + logf(ss[0]);
}

// ---------------- final ----------------
__global__ void final_kernel(const float* __restrict__ lt, const float* __restrict__ lse,
                             float* __restrict__ out, int LM, int KN) {
  int b = blockIdx.x, i = threadIdx.x;
  int base = (b * LM + i) * KN;
  float m = -INFINITY;
  for (int k = 0; k < KN; k++) m = fmaxf(m, lt[base + k] - lse[base + k]);
  float s = 0.f;
  for (int k = 0; k < KN; k++) s += expf(lt[base + k] - lse[base + k] - m);
  float cent = m + logf(s) - logf((float)KN);
#pragma unroll
  for (int o = 32; o > 0; o >>= 1) cent += __shfl_down(cent, o, 64);
  if (i == 0) out[b] = -cent / LM;
}

// ---------------- host dispatchers ----------------
// cfg: 0 = 128x128, 1 = 128x64, 2 = 64x64, 3 = 32x32 (tiny latency-bound shapes)
static inline void bgemm(hipStream_t st, int cfg, const short* A, int lda, long sA,
                         const short* B, int ldb, long sB,
                         void* C, int ldc, long sC, int M, int N, int Ksz, int nb,
                         float alpha, const float* bias, int relu, int out_bf16,
                         int shiftA, int shiftB, int ns1, int ns2, int Lroll,
                         int expo = 0, int asum = 0,
                         short* C2 = nullptr, int ldc2 = 0, int ncut = 0,
                         int ksplit = 1, long ksC = 0) {
  dim3 block(256);
  int nz = nb * ksplit;
#define BG_ARGS A, lda, sA, B, ldb, sB, C, ldc, sC, C2, ldc2, ncut, Ksz, alpha, bias, relu, expo, shiftA, shiftB, ns1, ns2, Lroll, ksplit, ksC
  if (cfg == 0) {
    dim3 grid(N / 128, M / 128, nz);
    if (out_bf16)
      bgemm_kernel<128, 128, 1, 0><<<grid, block, 0, st>>>(BG_ARGS);
    else
      bgemm_kernel<128, 128, 0, 0><<<grid, block, 0, st>>>(BG_ARGS);
  } else if (cfg == 1) {
    dim3 grid(N / 64, M / 128, nz);
    if (out_bf16) {
      if (asum)
        bgemm_kernel<128, 64, 1, 1><<<grid, block, 0, st>>>(BG_ARGS);
      else
        bgemm_kernel<128, 64, 1, 0><<<grid, block, 0, st>>>(BG_ARGS);
    } else {
      bgemm_kernel<128, 64, 0, 0><<<grid, block, 0, st>>>(BG_ARGS);
    }
  } else if (cfg == 2) {
    dim3 grid(N / 64, M / 64, nz);
    if (out_bf16)
      bgemm_kernel<64, 64, 1, 0><<<grid, block, 0, st>>>(BG_ARGS);
    else
      bgemm_kernel<64, 64, 0, 0><<<grid, block, 0, st>>>(BG_ARGS);
  } else {
    dim3 grid(N / 32, M / 32, nz);
    bgemm_kernel<32, 32, 1, 0><<<grid, block, 0, st>>>(BG_ARGS);
  }
#undef BG_ARGS
}

static inline void cvt(hipStream_t st, const float* src, short* dst, long n) {
  long n4 = n / 4;
  cvt_kernel<<<(int)((n4 + 255) / 256), 256, 0, st>>>(src, dst, n4);
}

static inline void cvt2(hipStream_t st, const float* src, short* dst, int R, int C,
                        int ldS, int ldD, long sS, long sD, int nb) {
  dim3 grid(C / 32, R / 32, nb), block(32, 8);
  cvt2_kernel<<<grid, block, 0, st>>>(src, dst, ldS, ldD, sS, sD);
}

static inline void cvtT2(hipStream_t st, const float* src, short* dst, int R, int C,
                         int ldS, int ldD, long sS, long sD, int nb) {
  dim3 grid(C / 32, R / 32, nb), block(32, 8);
  cvtT2_kernel<<<grid, block, 0, st>>>(src, dst, ldS, ldD, sS, sD);
}

extern "C" void kernel_launch(void* const* d_in, const int* in_sizes, int n_in,
                              void* d_out, int out_size, void* d_ws, size_t ws_size,
                              hipStream_t stream) {
  const int* masked = (const int*)d_in[0];
  const int* unmasked = (const int*)d_in[1];
  const int* mask = (const int*)d_in[2];
  const float* embed = (const float*)d_in[3];
  const float* Wt = (const float*)d_in[4];
  const float* bt = (const float*)d_in[5];
  const float* Wtc = (const float*)d_in[6];
  const float* Wq = (const float*)d_in[7];
  const float* Wd = (const float*)d_in[8];
  const float* Wo = (const float*)d_in[9];
  const float* Wu = (const float*)d_in[10];
  const float* Wem = (const float*)d_in[11];
  const float* Wkc = (const float*)d_in[12];
  const float* bkc = (const float*)d_in[13];

  const int B = out_size;                  // 4
  const int BL = in_sizes[0];              // 2048
  const int L = BL / B;                    // 512
  const int BLM = in_sizes[2];             // 256
  const int LM = BLM / B;                  // 64
  const int E = in_sizes[4] / in_sizes[5]; // 256
  const int D = in_sizes[5] / E;           // 6
  const int G = in_sizes[3] / E;           // 32000
  const int K = in_sizes[7] / (D * E * E); // 8
  const int KN = in_sizes[12] / (E * E);   // 4
  const int KE = K * E;                    // 2048
  const int N = LM * KN;                   // 256
  const float inv_sqrt_e = 1.0f / sqrtf((float)E);
  const int nch = G / 128;                 // 250
  const int E3 = 3 * E;                    // 768
  const int KA = E3 + KE;                  // 2816 = [t1a|t1b|z|r] concat-K width
  const int NQ = 2 * E + KE;               // 2560 = merged catA1+q output width

  // ---- workspace carve ----
  char* base = (char*)d_ws;
  size_t off = 0;
  auto carve = [&](size_t bytes) {
    char* p = base + off;
    off += (bytes + 255) & ~(size_t)255;
    return p;
  };
  float* xsa = (float*)carve((size_t)BL * E * 4);
  float* xsad = (float*)carve((size_t)2 * BL * E * 4);     // 2 split-K halves
  float* stM = (float*)carve((size_t)B * N * nch * 4);
  float* stS = (float*)carve((size_t)B * N * nch * 4);
  float* lse = (float*)carve((size_t)B * N * 4);
  float* lt = (float*)carve((size_t)B * N * 4);
  int* tgt = (int*)carve((size_t)B * LM * 4);
  short* xsa_bf = (short*)carve((size_t)BL * E * 2);
  short* xsaT_bf = (short*)carve((size_t)B * E * L * 2);
  short* catA = (short*)carve((size_t)BL * KA * 2);        // [t1a|t1b|z|r], ld KA
  short* qy_bf = (short*)carve((size_t)BL * KE * 2);
  short* hP_bf = (short*)carve((size_t)B * L * K * L * 2); // exp'd attention scores
  short* wd_all = (short*)carve((size_t)D * KE * KE * 2);
  short* BcatQ = (short*)carve((size_t)D * NQ * E * 2);    // [wtT; wtc; Wq] rows, ld E
  short* Bcat2x = (short*)carve((size_t)D * E * KA * 2);   // [wtcT|wt|wu|woT], ld KA
  short* embed_bf = (short*)carve((size_t)G * E * 2);
  short* WemT_bf = (short*)carve((size_t)E * E * 2);
  short* Wkc_bf = (short*)carve((size_t)KN * E * E * 2);
  short* gram_bf = (short*)carve((size_t)B * E * E * 2);
  short* xx_bf = (short*)carve((size_t)B * N * E * 2);
  short* xx2_bf = (short*)carve((size_t)B * N * E * 2);
  short* vv_bf = (short*)carve((size_t)B * N * E * 2);
  short* lptok_bf = (short*)carve((size_t)BLM * E * 2);

  // ---- up-front conversions ----
  cvt(stream, embed, embed_bf, (long)G * E);
  cvt(stream, Wd, wd_all, (long)D * KE * KE);
  cvt(stream, Wkc, Wkc_bf, (long)KN * E * E);
  cvtT2(stream, Wem, WemT_bf, E, E, E, E, 0, 0, 1);
  // BcatQ rows: [0,E)=wtT, [E,2E)=wtc, [2E,2E+KE)=Wq  (all NT B-operands, ld E)
  cvtT2(stream, Wt, BcatQ, E, E, E, E, (long)E * E, (long)NQ * E, D);
  cvt2(stream, Wtc, BcatQ + (size_t)E * E, E, E, E, E, (long)E * E, (long)NQ * E, D);
  cvt2(stream, Wq, BcatQ + (size_t)2 * E * E, KE, E, E, E, (long)KE * E, (long)NQ * E, D);
  // Bcat2x = [wtcT | wt | wu | woT], ld KA (NT B for catA @ [wtc; wtT; wuT; wo])
  cvtT2(stream, Wtc, Bcat2x, E, E, E, KA, (long)E * E, (long)E * KA, D);
  cvt2(stream, Wt, Bcat2x + E, E, E, E, KA, (long)E * E, (long)E * KA, D);
  cvt2(stream, Wu, Bcat2x + 2 * E, E, E, E, KA, (long)E * E, (long)E * KA, D);
  cvtT2(stream, Wo, Bcat2x + E3, KE, E, E, KA, (long)KE * E, (long)E * KA, D);

  // z = norm(embed[masked]); xsa = z (+bf16, +transposed, +catA z-slot)
  embed_norm_kernel<<<BL, E, 0, stream>>>(masked, embed, xsa, xsa_bf, xsaT_bf, catA,
                                          E, L, KA, 2 * E);

  const float log2e = 1.4426950408889634f;
  for (int d = 0; d < D; d++) {
    const float* btl = bt + (size_t)d * E;
    // merged: catA[:,0:512] = [relu(roll(xsa,+1)@wt) | relu(roll(xsa,-1)@wtcT)]
    //         qy            = xsa @ wq^T              (cols 512..2559, no relu)
    bgemm(stream, 1, xsa_bf, E, 0, BcatQ + (size_t)d * NQ * E, E, 0,
          catA, KA, 0, BL, NQ, E, 1, 1.f, nullptr, 1, 1,
          -1, +1, E, 2 * E, L, 0, 0, qy_bf, KE, 2 * E);
    // hP = exp(q . xsa^T / sqrt(E)) via exp2(alpha*h), alpha = log2e/sqrt(E)
    bgemm(stream, 0, qy_bf, E, (long)L * KE, xsa_bf, E, (long)L * E,
          hP_bf, L, (long)L * K * L, L * K, L, E, B, inv_sqrt_e * log2e, nullptr, 0, 1,
          0, 0, 0, 0, L, 1);
    // y = (P @ xsa) / rowsum(P)  — softmax normalization fused via ones-MFMA row sums
    bgemm(stream, 1, hP_bf, L, (long)L * K * L, xsaT_bf, L, (long)E * L,
          qy_bf, E, (long)L * KE, L * K, E, L, B, 1.f, nullptr, 0, 1,
          0, 0, 0, 0, L, 0, 1);
    // catA[:,768:2816] = r = relu(y @ wd^T)  (128x128 tile: 256 blocks, 1/CU)
    bgemm(stream, 0, qy_bf, KE, 0, wd_all + (size_t)d * KE * KE, KE, 0,
          catA + E3, KA, 0, BL, KE, KE, 1, 1.f, nullptr, 1, 1, 0, 0, 0, 0, L);
    // xsadt = catA @ [wtc; wtT; wuT; wo] + bt, split-K=2 into xsad[0],xsad[BL*E]
    bgemm(stream, 2, catA, KA, 0, Bcat2x + (size_t)d * E * KA, KA, 0,
          xsad, E, 0, BL, E, KA, 1, 1.f, btl, 0, 0, 0, 0, 0, 0, L,
          0, 0, nullptr, 0, 0, 2, (long)BL * E);
    addnorm_kernel<<<BL, E, 0, stream>>>(xsad, xsad + (size_t)BL * E,
                                         xsa, xsa_bf, xsaT_bf, E, L);
  }

  // ---- head ----
  gather_kernel<<<BLM, E, 0, stream>>>(xsa, mask, unmasked, lptok_bf, tgt, L, LM, E);
  // tiny head GEMMs on 32x32 tiles (cfg3): 256 blocks each = 1/CU, vs 64 at cfg2
  bgemm(stream, 3, xsaT_bf, L, (long)E * L, xsaT_bf, L, (long)E * L,
        gram_bf, E, (long)E * E, E, E, L, B, 1.f, nullptr, 0, 1, 0, 0, 0, 0, L);
  bgemm(stream, 3, lptok_bf, E, 0, Wkc_bf, E, 0, xx_bf, KN * E, 0, BLM, KN * E, E, 1,
        1.f, bkc, 0, 1, 0, 0, 0, 0, L);
  bgemm(stream, 3, xx_bf, E, (long)N * E, gram_bf, E, (long)E * E,
        xx2_bf, E, (long)N * E, N, E, E, B, 1.f, nullptr, 0, 1, 0, 0, 0, 0, L);
  bgemm(stream, 3, xx2_bf, E, 0, WemT_bf, E, 0, vv_bf, E, 0, B * N, E, E, 1,
        1.f, nullptr, 0, 1, 0, 0, 0, 0, L);
  {
    int nchPad = (nch + 7) & ~7;  // 256
    head_stats_kernel<<<nchPad * 16, 256, 0, stream>>>(vv_bf, embed_bf, stM, stS,
                                                       E, nch, B * N);
  }
  lse_logit_kernel<<<B * N, 256, 0, stream>>>(stM, stS, vv_bf, embed_bf, tgt,
                                              lse, lt, nch, B * N, E, N, KN, LM);
  final_kernel<<<B, LM, 0, stream>>>(lt, lse, (float*)d_out, LM, KN);
}